// Round 1
// baseline (177.154 us; speedup 1.0000x reference)
//
#include <hip/hip_runtime.h>
#include <stdint.h>

// Problem constants (static per reference)
#define NG    256    // graphs
#define NPG   128    // nodes per graph
#define PP    8      // perturbations
#define IND   64     // input dim
#define HID   128    // hidden
#define OUTD  10     // classes

typedef short bf16x8 __attribute__((ext_vector_type(8)));
typedef float f32x4  __attribute__((ext_vector_type(4)));

static __device__ __forceinline__ unsigned short f2bf(float f) {
    unsigned int u = __float_as_uint(f);
    u += 0x7FFFu + ((u >> 16) & 1u);
    return (unsigned short)(u >> 16);
}

static __device__ __forceinline__ f32x4 mfma16(bf16x8 a, bf16x8 b, f32x4 c) {
    return __builtin_amdgcn_mfma_f32_16x16x32_bf16(a, b, c, 0, 0, 0);
}

// Load 8 consecutive fp32 -> bf16x8 (B-operand fragment from global x)
static __device__ __forceinline__ bf16x8 cvt8(const float* __restrict__ p) {
    float4 lo = *(const float4*)p;
    float4 hi = *(const float4*)(p + 4);
    bf16x8 v;
    v[0] = (short)f2bf(lo.x); v[1] = (short)f2bf(lo.y);
    v[2] = (short)f2bf(lo.z); v[3] = (short)f2bf(lo.w);
    v[4] = (short)f2bf(hi.x); v[5] = (short)f2bf(hi.y);
    v[6] = (short)f2bf(hi.z); v[7] = (short)f2bf(hi.w);
    return v;
}

// ---------------------------------------------------------------------------
// Kernel 0: convert + transpose the six MFMA-side weights to bf16 Wt[out][in]
// ws layout (ushort elements):
//   [0)      W1t  128x64
//   [8192)   W2t  128x128
//   [24576)  Wg1t 128x128
//   [40960)  Wg2t 128x128
//   [57344)  Wb1t 128x128
//   [73728)  Wb2t 128x128   (total 90112 ushorts)
// ---------------------------------------------------------------------------
__global__ void prep_weights(const float* __restrict__ Wl1, const float* __restrict__ Wl2,
                             const float* __restrict__ Wg1, const float* __restrict__ Wg2,
                             const float* __restrict__ Wb1, const float* __restrict__ Wb2,
                             unsigned short* __restrict__ ws) {
    int e = blockIdx.x * blockDim.x + threadIdx.x;
    const float* src; unsigned short* dst; int K; int idx;
    if      (e <  8192) { src = Wl1; dst = ws;          K = 64;  idx = e;         }
    else if (e < 24576) { src = Wl2; dst = ws +  8192;  K = 128; idx = e -  8192; }
    else if (e < 40960) { src = Wg1; dst = ws + 24576;  K = 128; idx = e - 24576; }
    else if (e < 57344) { src = Wg2; dst = ws + 40960;  K = 128; idx = e - 40960; }
    else if (e < 73728) { src = Wb1; dst = ws + 57344;  K = 128; idx = e - 57344; }
    else if (e < 90112) { src = Wb2; dst = ws + 73728;  K = 128; idx = e - 73728; }
    else return;
    int k = idx >> 7;       // idx / 128  (source row, = contraction index)
    int n = idx & 127;      // source col (= out index)
    dst[n * K + k] = f2bf(src[idx]);
}

// ---------------------------------------------------------------------------
// Kernel 1: one block per graph, fully fused pipeline.
// 512 threads = 8 waves. wave w: a=w&3 -> out-tiles {2a,2a+1}; b=w>>2 -> row-tiles {4b..4b+3}
// Every matmul is computed as Y^T = Wt * X^T with 16x16x32 bf16 MFMA:
//   A-frag: Wt[ot*16+r][ks*32+q*8..+7]          (contiguous, regs/global)
//   B-frag: Xbuf[rt*16+r][ks*32+q*8..+7]        (contiguous, ds_read_b128 / global)
//   D:      lane holds Y[row=rt*16+r][out=ot*16+q*4+i]  -> ds_write_b64 of 4 bf16
// ---------------------------------------------------------------------------
#define LSTR 136   // LDS row stride in bf16 elements (128 + 8 pad; 272B, 16B aligned)

__global__ __launch_bounds__(512, 2) void fused_gnn(
    const float* __restrict__ x,
    const unsigned short* __restrict__ wt,
    const float* __restrict__ bl1, const float* __restrict__ bl2,
    const float* __restrict__ bg1, const float* __restrict__ bg2,
    const float* __restrict__ bb1, const float* __restrict__ bb2,
    const float* __restrict__ Wd1, const float* __restrict__ bd1,
    const float* __restrict__ Wd2, const float* __restrict__ bd2,
    float* __restrict__ out)
{
    __shared__ unsigned short buf0[128 * LSTR];
    __shared__ unsigned short buf1[128 * LSTR];
    __shared__ float pooled[HID];
    __shared__ float zbuf[80];

    const int g    = blockIdx.x;
    const int tid  = threadIdx.x;
    const int wave = tid >> 6;
    const int lane = tid & 63;
    const int q    = lane >> 4;
    const int r    = lane & 15;
    const int ot0  = (wave & 3) * 2;   // this wave's out-tiles: ot0, ot0+1
    const int rt0  = (wave >> 2) * 4;  // this wave's row-tiles: rt0..rt0+3

    if (tid < HID) pooled[tid] = 0.0f;

    // ---- phase-A weight fragments live in registers for the whole p-loop ----
    bf16x8 w1f[2][2];
#pragma unroll
    for (int t = 0; t < 2; ++t)
#pragma unroll
        for (int ks = 0; ks < 2; ++ks)
            w1f[t][ks] = *(const bf16x8*)(wt + ((ot0 + t) * 16 + r) * 64 + ks * 32 + q * 8);

    const unsigned short* w2t = wt + 8192;
    bf16x8 w2f[2][4];
#pragma unroll
    for (int t = 0; t < 2; ++t)
#pragma unroll
        for (int ks = 0; ks < 4; ++ks)
            w2f[t][ks] = *(const bf16x8*)(w2t + ((ot0 + t) * 16 + r) * 128 + ks * 32 + q * 8);

    f32x4 agg[2][4];
#pragma unroll
    for (int t = 0; t < 2; ++t)
#pragma unroll
        for (int j = 0; j < 4; ++j)
            agg[t][j] = (f32x4){0.f, 0.f, 0.f, 0.f};

    const float* xg = x + (size_t)g * (NPG * PP) * IND;

    // ================= Phase A: local MLP + perturbation sum =================
    for (int p = 0; p < PP; ++p) {
        unsigned short* h1 = (p & 1) ? buf1 : buf0;

        // ---- layer 1: h1^T = W1t * x^T  (K = 64) ----
        f32x4 acc[2][4];
#pragma unroll
        for (int t = 0; t < 2; ++t)
#pragma unroll
            for (int j = 0; j < 4; ++j)
                acc[t][j] = (f32x4){0.f, 0.f, 0.f, 0.f};

#pragma unroll
        for (int ks = 0; ks < 2; ++ks) {
#pragma unroll
            for (int j = 0; j < 4; ++j) {
                int row = p * 128 + (rt0 + j) * 16 + r;
                bf16x8 xf = cvt8(xg + row * IND + ks * 32 + q * 8);
                acc[0][j] = mfma16(w1f[0][ks], xf, acc[0][j]);
                acc[1][j] = mfma16(w1f[1][ks], xf, acc[1][j]);
            }
        }
        // bias + relu + bf16 store to H1 (row-major [row][hid])
#pragma unroll
        for (int t = 0; t < 2; ++t) {
            int ob = (ot0 + t) * 16 + q * 4;
            float4 bs = *(const float4*)(bl1 + ob);
#pragma unroll
            for (int j = 0; j < 4; ++j) {
                int row = (rt0 + j) * 16 + r;
                ushort4 v;
                v.x = f2bf(fmaxf(acc[t][j][0] + bs.x, 0.f));
                v.y = f2bf(fmaxf(acc[t][j][1] + bs.y, 0.f));
                v.z = f2bf(fmaxf(acc[t][j][2] + bs.z, 0.f));
                v.w = f2bf(fmaxf(acc[t][j][3] + bs.w, 0.f));
                *(ushort4*)(h1 + row * LSTR + ob) = v;
            }
        }
        __syncthreads();

        // ---- layer 2: h2^T = W2t * h1^T  (K = 128), accumulate relu into agg ----
        f32x4 acc2[2][4];
#pragma unroll
        for (int t = 0; t < 2; ++t)
#pragma unroll
            for (int j = 0; j < 4; ++j)
                acc2[t][j] = (f32x4){0.f, 0.f, 0.f, 0.f};

#pragma unroll
        for (int ks = 0; ks < 4; ++ks) {
#pragma unroll
            for (int j = 0; j < 4; ++j) {
                int row = (rt0 + j) * 16 + r;
                bf16x8 hf = *(const bf16x8*)(h1 + row * LSTR + ks * 32 + q * 8);
                acc2[0][j] = mfma16(w2f[0][ks], hf, acc2[0][j]);
                acc2[1][j] = mfma16(w2f[1][ks], hf, acc2[1][j]);
            }
        }
#pragma unroll
        for (int t = 0; t < 2; ++t) {
            int ob = (ot0 + t) * 16 + q * 4;
            float4 bs = *(const float4*)(bl2 + ob);
#pragma unroll
            for (int j = 0; j < 4; ++j) {
                agg[t][j][0] += fmaxf(acc2[t][j][0] + bs.x, 0.f);
                agg[t][j][1] += fmaxf(acc2[t][j][1] + bs.y, 0.f);
                agg[t][j][2] += fmaxf(acc2[t][j][2] + bs.z, 0.f);
                agg[t][j][3] += fmaxf(acc2[t][j][3] + bs.w, 0.f);
            }
        }
        // one barrier per p is sufficient with the double buffer (see analysis)
    }

    // write agg (bf16) into buf0 as the phase-B input activation [node][hid]
#pragma unroll
    for (int t = 0; t < 2; ++t) {
        int ob = (ot0 + t) * 16 + q * 4;
#pragma unroll
        for (int j = 0; j < 4; ++j) {
            int row = (rt0 + j) * 16 + r;
            ushort4 v;
            v.x = f2bf(agg[t][j][0]);
            v.y = f2bf(agg[t][j][1]);
            v.z = f2bf(agg[t][j][2]);
            v.w = f2bf(agg[t][j][3]);
            *(ushort4*)(buf0 + row * LSTR + ob) = v;
        }
    }
    __syncthreads();

    // ================= Phase B: 4x (Linear+ReLU) on [128 nodes][128] + pool ==
    int cur = 0;
#pragma unroll
    for (int l = 0; l < 4; ++l) {
        const unsigned short* wl = wt + 24576 + l * 16384;
        const float* bl = (l == 0) ? bg1 : (l == 1) ? bg2 : (l == 2) ? bb1 : bb2;

        bf16x8 wf[2][4];
#pragma unroll
        for (int t = 0; t < 2; ++t)
#pragma unroll
            for (int ks = 0; ks < 4; ++ks)
                wf[t][ks] = *(const bf16x8*)(wl + ((ot0 + t) * 16 + r) * 128 + ks * 32 + q * 8);

        unsigned short* Xb = cur ? buf1 : buf0;
        unsigned short* Yb = cur ? buf0 : buf1;

        f32x4 acc[2][4];
#pragma unroll
        for (int t = 0; t < 2; ++t)
#pragma unroll
            for (int j = 0; j < 4; ++j)
                acc[t][j] = (f32x4){0.f, 0.f, 0.f, 0.f};

#pragma unroll
        for (int ks = 0; ks < 4; ++ks) {
#pragma unroll
            for (int j = 0; j < 4; ++j) {
                int row = (rt0 + j) * 16 + r;
                bf16x8 xf = *(const bf16x8*)(Xb + row * LSTR + ks * 32 + q * 8);
                acc[0][j] = mfma16(wf[0][ks], xf, acc[0][j]);
                acc[1][j] = mfma16(wf[1][ks], xf, acc[1][j]);
            }
        }

        if (l < 3) {
#pragma unroll
            for (int t = 0; t < 2; ++t) {
                int ob = (ot0 + t) * 16 + q * 4;
                float4 bs = *(const float4*)(bl + ob);
#pragma unroll
                for (int j = 0; j < 4; ++j) {
                    int row = (rt0 + j) * 16 + r;
                    ushort4 v;
                    v.x = f2bf(fmaxf(acc[t][j][0] + bs.x, 0.f));
                    v.y = f2bf(fmaxf(acc[t][j][1] + bs.y, 0.f));
                    v.z = f2bf(fmaxf(acc[t][j][2] + bs.z, 0.f));
                    v.w = f2bf(fmaxf(acc[t][j][3] + bs.w, 0.f));
                    *(ushort4*)(Yb + row * LSTR + ob) = v;
                }
            }
            __syncthreads();
            cur ^= 1;
        } else {
            // final layer: bias+relu in fp32, pool over this wave's 64 rows
            float s[2][4];
#pragma unroll
            for (int t = 0; t < 2; ++t) {
                int ob = (ot0 + t) * 16 + q * 4;
                float4 bs = *(const float4*)(bl + ob);
                s[t][0] = s[t][1] = s[t][2] = s[t][3] = 0.f;
#pragma unroll
                for (int j = 0; j < 4; ++j) {
                    s[t][0] += fmaxf(acc[t][j][0] + bs.x, 0.f);
                    s[t][1] += fmaxf(acc[t][j][1] + bs.y, 0.f);
                    s[t][2] += fmaxf(acc[t][j][2] + bs.z, 0.f);
                    s[t][3] += fmaxf(acc[t][j][3] + bs.w, 0.f);
                }
            }
            // butterfly over the 16 r-lanes (rows) within each q group
#pragma unroll
            for (int m = 1; m < 16; m <<= 1) {
#pragma unroll
                for (int t = 0; t < 2; ++t)
#pragma unroll
                    for (int i = 0; i < 4; ++i)
                        s[t][i] += __shfl_xor(s[t][i], m, 64);
            }
            if (r == 0) {
#pragma unroll
                for (int t = 0; t < 2; ++t)
#pragma unroll
                    for (int i = 0; i < 4; ++i)
                        atomicAdd(&pooled[(ot0 + t) * 16 + q * 4 + i], s[t][i]);
            }
        }
    }
    __syncthreads();

    // ================= Phase C: decoder + log_softmax (fp32 VALU) ============
    if (tid < 64) {
        float a = bd1[tid];
#pragma unroll 4
        for (int k = 0; k < 128; ++k) a += pooled[k] * Wd1[k * 64 + tid];
        zbuf[tid] = fmaxf(a, 0.f);
    }
    __syncthreads();
    if (tid < OUTD) {
        float a = bd2[tid];
#pragma unroll 4
        for (int k = 0; k < 64; ++k) a += zbuf[k] * Wd2[k * OUTD + tid];
        zbuf[64 + tid] = a;
    }
    __syncthreads();
    if (tid == 0) {
        float m = -1e30f;
#pragma unroll
        for (int j = 0; j < OUTD; ++j) m = fmaxf(m, zbuf[64 + j]);
        float ssum = 0.f;
#pragma unroll
        for (int j = 0; j < OUTD; ++j) ssum += expf(zbuf[64 + j] - m);
        float ls = logf(ssum);
#pragma unroll
        for (int j = 0; j < OUTD; ++j) out[g * OUTD + j] = zbuf[64 + j] - m - ls;
    }
}

extern "C" void kernel_launch(void* const* d_in, const int* in_sizes, int n_in,
                              void* d_out, int out_size, void* d_ws, size_t ws_size,
                              hipStream_t stream) {
    const float* x   = (const float*)d_in[0];
    // d_in[1] = ptr (unused; structure is static)
    const float* Wl1 = (const float*)d_in[2];
    const float* bl1 = (const float*)d_in[3];
    const float* Wl2 = (const float*)d_in[4];
    const float* bl2 = (const float*)d_in[5];
    const float* Wg1 = (const float*)d_in[6];
    const float* bg1 = (const float*)d_in[7];
    const float* Wg2 = (const float*)d_in[8];
    const float* bg2 = (const float*)d_in[9];
    const float* Wb1 = (const float*)d_in[10];
    const float* bb1 = (const float*)d_in[11];
    const float* Wb2 = (const float*)d_in[12];
    const float* bb2 = (const float*)d_in[13];
    const float* Wd1 = (const float*)d_in[14];
    const float* bd1 = (const float*)d_in[15];
    const float* Wd2 = (const float*)d_in[16];
    const float* bd2 = (const float*)d_in[17];

    unsigned short* ws = (unsigned short*)d_ws;

    prep_weights<<<352, 256, 0, stream>>>(Wl1, Wl2, Wg1, Wg2, Wb1, Wb2, ws);
    fused_gnn<<<NG, 512, 0, stream>>>(x, ws, bl1, bl2, bg1, bg2, bb1, bb2,
                                      Wd1, bd1, Wd2, bd2, (float*)d_out);
}